// Round 13
// baseline (253.523 us; speedup 1.0000x reference)
//
#include <hip/hip_runtime.h>
#include <hip/hip_bf16.h>

#define BB 8
#define NN 4096
#define DD 64

typedef __attribute__((ext_vector_type(8))) short short8;
typedef __attribute__((ext_vector_type(4))) float f32x4;

__device__ __forceinline__ short f2bf(float f) {
    __hip_bfloat16 h = __float2bfloat16(f);
    return __builtin_bit_cast(short, h);
}

__device__ __forceinline__ float bcastf(float x, int l) {
    return __int_as_float(__builtin_amdgcn_readlane(__float_as_int(x), l));
}

// count of set bits in mask strictly below this lane (64-lane mbcnt idiom)
__device__ __forceinline__ int mbcnt64(unsigned long long mask) {
    return __builtin_amdgcn_mbcnt_hi((unsigned)(mask >> 32),
           __builtin_amdgcn_mbcnt_lo((unsigned)mask, 0));
}

// ---------------- exact kNN: wave = 1 query (round-10 proven state machine) ----------------
__device__ __forceinline__ void bsort64(float& d, int& i, int lane) {
#pragma unroll
    for (int s = 2; s <= 64; s <<= 1) {
#pragma unroll
        for (int m = s >> 1; m >= 1; m >>= 1) {
            float dp = __shfl_xor(d, m);
            int ip = __shfl_xor(i, m);
            bool up = ((lane & s) == 0);
            bool lower = ((lane & m) == 0);
            bool less = (d < dp) || (d == dp && i < ip);
            bool takeMine = (less == (up == lower));
            d = takeMine ? d : dp;
            i = takeMine ? i : ip;
        }
    }
}

__device__ __forceinline__ float sq3(float x, float y, float z) {
    return __fadd_rn(__fadd_rn(__fmul_rn(x, x), __fmul_rn(y, y)), __fmul_rn(z, z));
}

// dist from precomputed-sq float4 entry; rounding chain identical to prior pdist
__device__ __forceinline__ float pdistv(float qx, float qy, float qz, float sqq, float4 c4) {
    float dot = __fadd_rn(__fadd_rn(__fmul_rn(qx, c4.x), __fmul_rn(qy, c4.y)),
                          __fmul_rn(qz, c4.z));
    return __fadd_rn(__fadd_rn(sqq, c4.w), -__fmul_rn(2.0f, dot));
}

// single-query insert region, text verbatim from the passing round-10 kernel.
// uses (and updates) the enclosing scope's: bD, bI, count, t, lane.
#define TAKE16(dc, cidx)                                              \
    {                                                                 \
        bool live = (dc) < t;                                         \
        unsigned long long mask = __ballot(live);                     \
        while (mask) {                                                \
            int avail = 64 - count;                                   \
            int pos = mbcnt64(mask);                                  \
            if (live && pos < avail) {                                \
                bD[count + pos] = (dc);                               \
                bI[count + pos] = (cidx);                             \
            }                                                         \
            int nq = __popcll(mask);                                  \
            if (nq <= avail) {                                        \
                count += nq;                                          \
                mask = 0;                                             \
            } else {                                                  \
                count = 64;                                           \
                live = live && (pos >= avail);                        \
                float sd = bD[lane];                                  \
                int si = bI[lane];                                    \
                bsort64(sd, si, lane);                                \
                if (lane < 16) { bD[lane] = sd; bI[lane] = si; }      \
                count = 16;                                           \
                t = __shfl(sd, 15);                                   \
                live = live && ((dc) < t);                            \
                mask = __ballot(live);                                \
            }                                                         \
        }                                                             \
    }

// block = 1024 threads = 16 waves sharing one X4 stage; 64 queries per block (4 per wave)
// grid = BB * 64 = 512 blocks; LDS 72KB -> 2 blocks/CU -> 8 waves/SIMD.
__global__ __launch_bounds__(1024) void knn_kernel(const float* __restrict__ xyz,
                                                   int* __restrict__ knnIdx) {
    __shared__ __align__(16) float4 X4[NN];     // (x,y,z,|c|^2), 64KB
    __shared__ float bufD[16][64];
    __shared__ int bufI[16][64];
    int tid = threadIdx.x;
    int b = blockIdx.x >> 6;        // 64 blocks per batch
    int qgroup = blockIdx.x & 63;   // 64 queries per block
    const float* xb = xyz + (size_t)b * NN * 3;
    for (int i = tid; i < NN; i += 1024) {
        float x = xb[i * 3], y = xb[i * 3 + 1], z = xb[i * 3 + 2];
        X4[i] = make_float4(x, y, z, sq3(x, y, z));
    }
    __syncthreads();

    int wid = tid >> 6, lane = tid & 63;
    float* bD = bufD[wid];
    int* bI = bufI[wid];

    for (int qi = 0; qi < 4; ++qi) {
        int qq = qgroup * 64 + wid * 4 + qi;
        float4 qv = X4[qq];
        float qx = qv.x, qy = qv.y, qz = qv.z, sqq = qv.w;
        // round 0: candidates 0..63
        float d0 = pdistv(qx, qy, qz, sqq, X4[lane]);
        int i0 = lane;
        bsort64(d0, i0, lane);
        if (lane < 16) { bD[lane] = d0; bI[lane] = i0; }
        int count = 16;
        float t = __shfl(d0, 15);

        // rounds 1..62 as 31 pairs: both loads + dist chains issued straight-line,
        // then two sequential TAKE regions in exact candidate order.
        for (int r = 1; r < 63; r += 2) {
            int ia = r * 64 + lane;
            int ib = ia + 64;
            float4 ca = X4[ia];
            float4 cb = X4[ib];
            float dca = pdistv(qx, qy, qz, sqq, ca);
            float dcb = pdistv(qx, qy, qz, sqq, cb);
            TAKE16(dca, ia)
            TAKE16(dcb, ib)
        }
        // final round 63
        {
            int ic = 63 * 64 + lane;
            float dcc = pdistv(qx, qy, qz, sqq, X4[ic]);
            TAKE16(dcc, ic)
        }

        float fd = (lane < count) ? bD[lane] : 3.0e38f;
        int fi = (lane < count) ? bI[lane] : 0x7fffffff;
        bsort64(fd, fi, lane);
        if (lane < 16) knnIdx[((size_t)b * NN + qq) * 16 + lane] = fi;
    }
}

// ---------------- q/k/v projections (f32, readlane broadcast) + stats zeroing ----------------
__global__ __launch_bounds__(256) void qkv_kernel(const float* __restrict__ feats,
                                                  const float* __restrict__ Wq,
                                                  const float* __restrict__ Wk,
                                                  const float* __restrict__ Wv,
                                                  float* __restrict__ Q,
                                                  float* __restrict__ Kf,
                                                  float* __restrict__ Vf,
                                                  float* __restrict__ stats) {
    __shared__ float Aq[4096], Ak[4096], Av[4096];
    int tid = threadIdx.x;
    if (blockIdx.x == 0 && tid < 128) stats[tid] = 0.f;
    for (int i = tid; i < 4096; i += 256) { Aq[i] = Wq[i]; Ak[i] = Wk[i]; Av[i] = Wv[i]; }
    __syncthreads();
    int lane = tid & 63, wid = tid >> 6;
    int gw = blockIdx.x * 4 + wid, nw = gridDim.x * 4;
    for (int r = gw; r < BB * NN; r += nw) {
        float f = feats[(size_t)r * 64 + lane];
        float aq = 0.f, ak = 0.f, av = 0.f;
#pragma unroll 8
        for (int h = 0; h < 64; ++h) {
            float s = bcastf(f, h);
            aq = fmaf(s, Aq[h * 64 + lane], aq);
            ak = fmaf(s, Ak[h * 64 + lane], ak);
            av = fmaf(s, Av[h * 64 + lane], av);
        }
        Q[(size_t)r * 64 + lane] = aq;
        Kf[(size_t)r * 64 + lane] = ak;
        Vf[(size_t)r * 64 + lane] = av;
    }
}

// ---------------- fused MFMA attention: wave = 1 point ----------------
#define TSTR 68

__global__ __launch_bounds__(256, 2) void attn_kernel(
    const float* __restrict__ xyz, const float* __restrict__ feats,
    const float* __restrict__ Q, const float* __restrict__ Kf, const float* __restrict__ Vf,
    const int* __restrict__ knnIdx,
    const float* __restrict__ d1w, const float* __restrict__ d1b,
    const float* __restrict__ d2w, const float* __restrict__ d2b,
    const float* __restrict__ g1w, const float* __restrict__ g1b,
    const float* __restrict__ g2w, const float* __restrict__ g2b,
    float* __restrict__ out, float* __restrict__ gsum, float* __restrict__ gsq) {
    __shared__ float d1s[4][64];
    __shared__ __align__(16) float tbuf[4][16 * TSTR];
    __shared__ float bns[64], bnq[64];
    int tid = threadIdx.x;
    if (tid < 256) {
        int a = tid >> 6, ch = tid & 63;
        d1s[a][ch] = (a < 3) ? d1w[a * 64 + ch] : d1b[ch];
    }
    if (tid < 64) { bns[tid] = 0.f; bnq[tid] = 0.f; }
    __syncthreads();

    int lane = tid & 63, wid = tid >> 6;
    int cc = lane & 15, g = lane >> 4;
    float* tb = tbuf[wid];

    short8 bd2[2][4], bg1[2][4], bg2[2][4];
#pragma unroll
    for (int kt = 0; kt < 2; ++kt)
#pragma unroll
        for (int ct = 0; ct < 4; ++ct) {
            short8 f2, fg1, fg2;
#pragma unroll
            for (int j = 0; j < 8; ++j) {
                int kk = kt * 32 + g * 8 + j, col = ct * 16 + cc;
                f2[j] = f2bf(d2w[kk * 64 + col]);
                fg1[j] = f2bf(g1w[kk * 64 + col]);
                fg2[j] = f2bf(g2w[kk * 64 + col]);
            }
            bd2[kt][ct] = f2; bg1[kt][ct] = fg1; bg2[kt][ct] = fg2;
        }
    float b2c[4], gb1c[4], gb2c[4];
#pragma unroll
    for (int ct = 0; ct < 4; ++ct) {
        b2c[ct] = d2b[ct * 16 + cc];
        gb1c[ct] = g1b[ct * 16 + cc];
        gb2c[ct] = g2b[ct * 16 + cc];
    }
    bool is1 = (g == 1), is2 = (g == 2), is3 = (g == 3);

    int gw = blockIdx.x * 4 + wid, nw = gridDim.x * 4;
    float lsum = 0.f, lsq = 0.f;

    for (int p = gw; p < BB * NN; p += nw) {
        int b = p >> 12;
        int idxA = knnIdx[(size_t)p * 16 + cc];
        int nb = (b << 12) + idxA;

        const float* Qp = Q + (size_t)p * 64;
        const float* Kp = Kf + (size_t)nb * 64;
        f32x4 q0 = *(const f32x4*)&Qp[g * 8], q1 = *(const f32x4*)&Qp[g * 8 + 4];
        f32x4 q2 = *(const f32x4*)&Qp[32 + g * 8], q3 = *(const f32x4*)&Qp[32 + g * 8 + 4];
        f32x4 k0 = *(const f32x4*)&Kp[g * 8], k1 = *(const f32x4*)&Kp[g * 8 + 4];
        f32x4 k2 = *(const f32x4*)&Kp[32 + g * 8], k3 = *(const f32x4*)&Kp[32 + g * 8 + 4];

        float sx = xyz[(size_t)p * 3], sy = xyz[(size_t)p * 3 + 1], sz = xyz[(size_t)p * 3 + 2];
        float dx = sx - xyz[(size_t)nb * 3];
        float dy = sy - xyz[(size_t)nb * 3 + 1];
        float dz = sz - xyz[(size_t)nb * 3 + 2];

        short8 ha[2];
#pragma unroll
        for (int kt = 0; kt < 2; ++kt) {
            short8 hv;
#pragma unroll
            for (int hb = 0; hb < 2; ++hb) {
                int ch = kt * 32 + g * 8 + hb * 4;
                f32x4 w0 = *(const f32x4*)&d1s[0][ch];
                f32x4 w1 = *(const f32x4*)&d1s[1][ch];
                f32x4 w2 = *(const f32x4*)&d1s[2][ch];
                f32x4 bb_ = *(const f32x4*)&d1s[3][ch];
#pragma unroll
                for (int j = 0; j < 4; ++j) {
                    float h = bb_[j] + dx * w0[j] + dy * w1[j] + dz * w2[j];
                    hv[hb * 4 + j] = f2bf(fmaxf(h, 0.f));
                }
            }
            ha[kt] = hv;
        }

        f32x4 pe[4];
#pragma unroll
        for (int ct = 0; ct < 4; ++ct) {
            f32x4 acc = {0.f, 0.f, 0.f, 0.f};
            acc = __builtin_amdgcn_mfma_f32_16x16x32_bf16(ha[0], bd2[0][ct], acc, 0, 0, 0);
            acc = __builtin_amdgcn_mfma_f32_16x16x32_bf16(ha[1], bd2[1][ct], acc, 0, 0, 0);
#pragma unroll
            for (int r = 0; r < 4; ++r) pe[ct][r] = acc[r] + b2c[ct];
        }

#pragma unroll
        for (int ct = 0; ct < 4; ++ct)
#pragma unroll
            for (int r = 0; r < 4; ++r)
                tb[(4 * g + r) * TSTR + ct * 16 + cc] = pe[ct][r];
        short8 xa[2];
        {
            f32x4 p0 = *(const f32x4*)&tb[cc * TSTR + g * 8];
            f32x4 p1 = *(const f32x4*)&tb[cc * TSTR + g * 8 + 4];
            f32x4 p2 = *(const f32x4*)&tb[cc * TSTR + 32 + g * 8];
            f32x4 p3 = *(const f32x4*)&tb[cc * TSTR + 32 + g * 8 + 4];
            f32x4 x0 = q0 - k0 + p0, x1 = q1 - k1 + p1;
            f32x4 x2 = q2 - k2 + p2, x3 = q3 - k3 + p3;
            short8 v0, v1;
#pragma unroll
            for (int j = 0; j < 4; ++j) {
                v0[j] = f2bf(x0[j]); v0[4 + j] = f2bf(x1[j]);
                v1[j] = f2bf(x2[j]); v1[4 + j] = f2bf(x3[j]);
            }
            xa[0] = v0; xa[1] = v1;
        }

        f32x4 h2[4];
#pragma unroll
        for (int ct = 0; ct < 4; ++ct) {
            f32x4 acc = {0.f, 0.f, 0.f, 0.f};
            acc = __builtin_amdgcn_mfma_f32_16x16x32_bf16(xa[0], bg1[0][ct], acc, 0, 0, 0);
            acc = __builtin_amdgcn_mfma_f32_16x16x32_bf16(xa[1], bg1[1][ct], acc, 0, 0, 0);
#pragma unroll
            for (int r = 0; r < 4; ++r) h2[ct][r] = fmaxf(acc[r] + gb1c[ct], 0.f);
        }

#pragma unroll
        for (int ct = 0; ct < 4; ++ct)
#pragma unroll
            for (int r = 0; r < 4; ++r)
                tb[(4 * g + r) * TSTR + ct * 16 + cc] = h2[ct][r];
        short8 h2a[2];
        {
            f32x4 p0 = *(const f32x4*)&tb[cc * TSTR + g * 8];
            f32x4 p1 = *(const f32x4*)&tb[cc * TSTR + g * 8 + 4];
            f32x4 p2 = *(const f32x4*)&tb[cc * TSTR + 32 + g * 8];
            f32x4 p3 = *(const f32x4*)&tb[cc * TSTR + 32 + g * 8 + 4];
            short8 v0, v1;
#pragma unroll
            for (int j = 0; j < 4; ++j) {
                v0[j] = f2bf(p0[j]); v0[4 + j] = f2bf(p1[j]);
                v1[j] = f2bf(p2[j]); v1[4 + j] = f2bf(p3[j]);
            }
            h2a[0] = v0; h2a[1] = v1;
        }

        f32x4 lg[4];
#pragma unroll
        for (int ct = 0; ct < 4; ++ct) {
            f32x4 acc = {0.f, 0.f, 0.f, 0.f};
            acc = __builtin_amdgcn_mfma_f32_16x16x32_bf16(h2a[0], bg2[0][ct], acc, 0, 0, 0);
            acc = __builtin_amdgcn_mfma_f32_16x16x32_bf16(h2a[1], bg2[1][ct], acc, 0, 0, 0);
#pragma unroll
            for (int r = 0; r < 4; ++r) lg[ct][r] = acc[r] + gb2c[ct];
        }

        const float* Vp = Vf + (size_t)nb * 64;
        {
            f32x4 v0 = *(const f32x4*)&Vp[g * 8], v1 = *(const f32x4*)&Vp[g * 8 + 4];
            f32x4 v2 = *(const f32x4*)&Vp[32 + g * 8], v3 = *(const f32x4*)&Vp[32 + g * 8 + 4];
            *(f32x4*)&tb[cc * TSTR + g * 8] = v0;
            *(f32x4*)&tb[cc * TSTR + g * 8 + 4] = v1;
            *(f32x4*)&tb[cc * TSTR + 32 + g * 8] = v2;
            *(f32x4*)&tb[cc * TSTR + 32 + g * 8 + 4] = v3;
        }
        f32x4 vc[4];
#pragma unroll
        for (int ct = 0; ct < 4; ++ct)
#pragma unroll
            for (int r = 0; r < 4; ++r)
                vc[ct][r] = tb[(4 * g + r) * TSTR + ct * 16 + cc];

        float part[4];
#pragma unroll
        for (int ct = 0; ct < 4; ++ct) {
            float m = fmaxf(fmaxf(lg[ct][0], lg[ct][1]), fmaxf(lg[ct][2], lg[ct][3]));
            m = fmaxf(m, __shfl_xor(m, 16));
            m = fmaxf(m, __shfl_xor(m, 32));
            float e0 = __expf(lg[ct][0] - m), e1 = __expf(lg[ct][1] - m);
            float e2 = __expf(lg[ct][2] - m), e3 = __expf(lg[ct][3] - m);
            float s = e0 + e1 + e2 + e3;
            s += __shfl_xor(s, 16);
            s += __shfl_xor(s, 32);
            float inv = 1.0f / s;
            float pt = 0.f;
            pt = fmaf(e0 * inv, vc[ct][0] + pe[ct][0], pt);
            pt = fmaf(e1 * inv, vc[ct][1] + pe[ct][1], pt);
            pt = fmaf(e2 * inv, vc[ct][2] + pe[ct][2], pt);
            pt = fmaf(e3 * inv, vc[ct][3] + pe[ct][3], pt);
            pt += __shfl_xor(pt, 16);
            pt += __shfl_xor(pt, 32);
            part[ct] = pt;
        }
        float resv = part[0];
        resv = is1 ? part[1] : resv;
        resv = is2 ? part[2] : resv;
        resv = is3 ? part[3] : resv;
        resv += feats[(size_t)p * 64 + lane];
        out[(size_t)p * 64 + lane] = resv;
        lsum += resv;
        lsq = fmaf(resv, resv, lsq);
    }
    atomicAdd(&bns[lane], lsum);
    atomicAdd(&bnq[lane], lsq);
    __syncthreads();
    if (tid < 64) {
        atomicAdd(&gsum[tid], bns[tid]);
        atomicAdd(&gsq[tid], bnq[tid]);
    }
}

// ---------------- BatchNorm finalize (in place on d_out) ----------------
__global__ __launch_bounds__(256) void bn_final_kernel(float* __restrict__ out,
                                                       const float* __restrict__ gsum,
                                                       const float* __restrict__ gsq,
                                                       const float* __restrict__ bnw,
                                                       const float* __restrict__ bnb) {
    __shared__ float sc[64], sh[64];
    int tid = threadIdx.x;
    if (tid < 64) {
        const float invN = 1.0f / (float)(BB * NN);
        float mean = gsum[tid] * invN;
        float var = gsq[tid] * invN - mean * mean;
        float inv = rsqrtf(var + 1e-5f);
        float scale = inv * bnw[tid];
        sc[tid] = scale;
        sh[tid] = bnb[tid] - mean * scale;
    }
    __syncthreads();
    size_t total = (size_t)BB * NN * 64;
    for (size_t i = (size_t)blockIdx.x * 256 + tid; i < total; i += (size_t)gridDim.x * 256) {
        int c = (int)(i & 63);
        out[i] = fmaf(out[i], sc[c], sh[c]);
    }
}

extern "C" void kernel_launch(void* const* d_in, const int* in_sizes, int n_in,
                              void* d_out, int out_size, void* d_ws, size_t ws_size,
                              hipStream_t stream) {
    const float* xyz = (const float*)d_in[0];
    const float* feats = (const float*)d_in[1];
    const float* Wq = (const float*)d_in[2];
    const float* Wk = (const float*)d_in[3];
    const float* Wv = (const float*)d_in[4];
    const float* d1w = (const float*)d_in[5];
    const float* d1b = (const float*)d_in[6];
    const float* d2w = (const float*)d_in[7];
    const float* d2b = (const float*)d_in[8];
    const float* g1w = (const float*)d_in[9];
    const float* g1b = (const float*)d_in[10];
    const float* g2w = (const float*)d_in[11];
    const float* g2b = (const float*)d_in[12];
    const float* bnw = (const float*)d_in[13];
    const float* bnb = (const float*)d_in[14];
    float* out = (float*)d_out;

    char* ws = (char*)d_ws;
    size_t off = 0;
    int* knnIdx = (int*)(ws + off); off += (size_t)BB * NN * 16 * 4;
    float* Q = (float*)(ws + off); off += (size_t)BB * NN * 64 * 4;
    float* Kf = (float*)(ws + off); off += (size_t)BB * NN * 64 * 4;
    float* Vf = (float*)(ws + off); off += (size_t)BB * NN * 64 * 4;
    float* stats = (float*)(ws + off);  // 128 floats

    hipLaunchKernelGGL(qkv_kernel, dim3(512), dim3(256), 0, stream,
                       feats, Wq, Wk, Wv, Q, Kf, Vf, stats);
    hipLaunchKernelGGL(knn_kernel, dim3(BB * 64), dim3(1024), 0, stream, xyz, knnIdx);
    hipLaunchKernelGGL(attn_kernel, dim3(512), dim3(256), 0, stream,
                       xyz, feats, Q, Kf, Vf, knnIdx,
                       d1w, d1b, d2w, d2b, g1w, g1b, g2w, g2b,
                       out, stats, stats + 64);
    hipLaunchKernelGGL(bn_final_kernel, dim3(512), dim3(256), 0, stream,
                       out, stats, stats + 64, bnw, bnb);
}

// Round 14
// 245.930 us; speedup vs baseline: 1.0309x; 1.0309x over previous
//
#include <hip/hip_runtime.h>
#include <hip/hip_bf16.h>

#define BB 8
#define NN 4096
#define DD 64

typedef __attribute__((ext_vector_type(8))) short short8;
typedef __attribute__((ext_vector_type(4))) float f32x4;

__device__ __forceinline__ short f2bf(float f) {
    __hip_bfloat16 h = __float2bfloat16(f);
    return __builtin_bit_cast(short, h);
}

__device__ __forceinline__ float bcastf(float x, int l) {
    return __int_as_float(__builtin_amdgcn_readlane(__float_as_int(x), l));
}

// count of set bits in mask strictly below this lane (64-lane mbcnt idiom)
__device__ __forceinline__ int mbcnt64(unsigned long long mask) {
    return __builtin_amdgcn_mbcnt_hi((unsigned)(mask >> 32),
           __builtin_amdgcn_mbcnt_lo((unsigned)mask, 0));
}

// ---------------- exact kNN: wave = 1 query (round-10 proven kernel, verbatim) ----------------
__device__ __forceinline__ void bsort64(float& d, int& i, int lane) {
#pragma unroll
    for (int s = 2; s <= 64; s <<= 1) {
#pragma unroll
        for (int m = s >> 1; m >= 1; m >>= 1) {
            float dp = __shfl_xor(d, m);
            int ip = __shfl_xor(i, m);
            bool up = ((lane & s) == 0);
            bool lower = ((lane & m) == 0);
            bool less = (d < dp) || (d == dp && i < ip);
            bool takeMine = (less == (up == lower));
            d = takeMine ? d : dp;
            i = takeMine ? i : ip;
        }
    }
}

__device__ __forceinline__ float sq3(float x, float y, float z) {
    return __fadd_rn(__fadd_rn(__fmul_rn(x, x), __fmul_rn(y, y)), __fmul_rn(z, z));
}

// dist from precomputed-sq float4 entry; rounding chain identical to prior pdist
__device__ __forceinline__ float pdistv(float qx, float qy, float qz, float sqq, float4 c4) {
    float dot = __fadd_rn(__fadd_rn(__fmul_rn(qx, c4.x), __fmul_rn(qy, c4.y)),
                          __fmul_rn(qz, c4.z));
    return __fadd_rn(__fadd_rn(sqq, c4.w), -__fmul_rn(2.0f, dot));
}

// block = 1024 threads = 16 waves sharing one X4 stage; 64 queries per block (4 per wave)
// grid = BB * 64 = 512 blocks; LDS 72KB -> 2 blocks/CU -> 8 waves/SIMD.
__global__ __launch_bounds__(1024) void knn_kernel(const float* __restrict__ xyz,
                                                   int* __restrict__ knnIdx) {
    __shared__ __align__(16) float4 X4[NN];     // (x,y,z,|c|^2), 64KB
    __shared__ float bufD[16][64];
    __shared__ int bufI[16][64];
    int tid = threadIdx.x;
    int b = blockIdx.x >> 6;        // 64 blocks per batch
    int qgroup = blockIdx.x & 63;   // 64 queries per block
    const float* xb = xyz + (size_t)b * NN * 3;
    for (int i = tid; i < NN; i += 1024) {
        float x = xb[i * 3], y = xb[i * 3 + 1], z = xb[i * 3 + 2];
        X4[i] = make_float4(x, y, z, sq3(x, y, z));
    }
    __syncthreads();

    int wid = tid >> 6, lane = tid & 63;
    float* bD = bufD[wid];
    int* bI = bufI[wid];

    for (int qi = 0; qi < 4; ++qi) {
        int qq = qgroup * 64 + wid * 4 + qi;
        float4 qv = X4[qq];
        float qx = qv.x, qy = qv.y, qz = qv.z, sqq = qv.w;
        // round 0: candidates 0..63
        float d0 = pdistv(qx, qy, qz, sqq, X4[lane]);
        int i0 = lane;
        bsort64(d0, i0, lane);
        if (lane < 16) { bD[lane] = d0; bI[lane] = i0; }
        int count = 16;
        float t = __shfl(d0, 15);

        for (int r = 1; r < 64; ++r) {
            int cidx = r * 64 + lane;
            float dc = pdistv(qx, qy, qz, sqq, X4[cidx]);
            bool live = dc < t;
            unsigned long long mask = __ballot(live);
            while (mask) {
                int avail = 64 - count;
                int pos = mbcnt64(mask);
                if (live && pos < avail) {
                    bD[count + pos] = dc;
                    bI[count + pos] = cidx;
                }
                int nq = __popcll(mask);
                if (nq <= avail) {
                    count += nq;
                    mask = 0;
                } else {
                    count = 64;
                    live = live && (pos >= avail);
                    // sort-cut to exact top-16 of all seen so far
                    float sd = bD[lane];
                    int si = bI[lane];
                    bsort64(sd, si, lane);
                    if (lane < 16) { bD[lane] = sd; bI[lane] = si; }
                    count = 16;
                    t = __shfl(sd, 15);
                    live = live && (dc < t);
                    mask = __ballot(live);
                }
            }
        }
        float fd = (lane < count) ? bD[lane] : 3.0e38f;
        int fi = (lane < count) ? bI[lane] : 0x7fffffff;
        bsort64(fd, fi, lane);
        if (lane < 16) knnIdx[((size_t)b * NN + qq) * 16 + lane] = fi;
    }
}

// ---------------- q/k/v projections (f32, readlane broadcast) + stats zeroing ----------------
__global__ __launch_bounds__(256) void qkv_kernel(const float* __restrict__ feats,
                                                  const float* __restrict__ Wq,
                                                  const float* __restrict__ Wk,
                                                  const float* __restrict__ Wv,
                                                  float* __restrict__ Q,
                                                  float* __restrict__ Kf,
                                                  float* __restrict__ Vf,
                                                  float* __restrict__ stats) {
    __shared__ float Aq[4096], Ak[4096], Av[4096];
    int tid = threadIdx.x;
    if (blockIdx.x == 0 && tid < 128) stats[tid] = 0.f;
    for (int i = tid; i < 4096; i += 256) { Aq[i] = Wq[i]; Ak[i] = Wk[i]; Av[i] = Wv[i]; }
    __syncthreads();
    int lane = tid & 63, wid = tid >> 6;
    int gw = blockIdx.x * 4 + wid, nw = gridDim.x * 4;
    for (int r = gw; r < BB * NN; r += nw) {
        float f = feats[(size_t)r * 64 + lane];
        float aq = 0.f, ak = 0.f, av = 0.f;
#pragma unroll 8
        for (int h = 0; h < 64; ++h) {
            float s = bcastf(f, h);
            aq = fmaf(s, Aq[h * 64 + lane], aq);
            ak = fmaf(s, Ak[h * 64 + lane], ak);
            av = fmaf(s, Av[h * 64 + lane], av);
        }
        Q[(size_t)r * 64 + lane] = aq;
        Kf[(size_t)r * 64 + lane] = ak;
        Vf[(size_t)r * 64 + lane] = av;
    }
}

// ---------------- fused MFMA attention: wave = 1 point ----------------
#define TSTR 68

__global__ __launch_bounds__(256, 2) void attn_kernel(
    const float* __restrict__ xyz, const float* __restrict__ feats,
    const float* __restrict__ Q, const float* __restrict__ Kf, const float* __restrict__ Vf,
    const int* __restrict__ knnIdx,
    const float* __restrict__ d1w, const float* __restrict__ d1b,
    const float* __restrict__ d2w, const float* __restrict__ d2b,
    const float* __restrict__ g1w, const float* __restrict__ g1b,
    const float* __restrict__ g2w, const float* __restrict__ g2b,
    float* __restrict__ out, float* __restrict__ gsum, float* __restrict__ gsq) {
    __shared__ float d1s[4][64];
    __shared__ __align__(16) float tbuf[4][16 * TSTR];
    __shared__ float bns[64], bnq[64];
    int tid = threadIdx.x;
    if (tid < 256) {
        int a = tid >> 6, ch = tid & 63;
        d1s[a][ch] = (a < 3) ? d1w[a * 64 + ch] : d1b[ch];
    }
    if (tid < 64) { bns[tid] = 0.f; bnq[tid] = 0.f; }
    __syncthreads();

    int lane = tid & 63, wid = tid >> 6;
    int cc = lane & 15, g = lane >> 4;
    float* tb = tbuf[wid];

    short8 bd2[2][4], bg1[2][4], bg2[2][4];
#pragma unroll
    for (int kt = 0; kt < 2; ++kt)
#pragma unroll
        for (int ct = 0; ct < 4; ++ct) {
            short8 f2, fg1, fg2;
#pragma unroll
            for (int j = 0; j < 8; ++j) {
                int kk = kt * 32 + g * 8 + j, col = ct * 16 + cc;
                f2[j] = f2bf(d2w[kk * 64 + col]);
                fg1[j] = f2bf(g1w[kk * 64 + col]);
                fg2[j] = f2bf(g2w[kk * 64 + col]);
            }
            bd2[kt][ct] = f2; bg1[kt][ct] = fg1; bg2[kt][ct] = fg2;
        }
    float b2c[4], gb1c[4], gb2c[4];
#pragma unroll
    for (int ct = 0; ct < 4; ++ct) {
        b2c[ct] = d2b[ct * 16 + cc];
        gb1c[ct] = g1b[ct * 16 + cc];
        gb2c[ct] = g2b[ct * 16 + cc];
    }
    bool is1 = (g == 1), is2 = (g == 2), is3 = (g == 3);

    int gw = blockIdx.x * 4 + wid, nw = gridDim.x * 4;
    float lsum = 0.f, lsq = 0.f;

    for (int p = gw; p < BB * NN; p += nw) {
        int b = p >> 12;
        int idxA = knnIdx[(size_t)p * 16 + cc];
        int nb = (b << 12) + idxA;

        const float* Qp = Q + (size_t)p * 64;
        const float* Kp = Kf + (size_t)nb * 64;
        f32x4 q0 = *(const f32x4*)&Qp[g * 8], q1 = *(const f32x4*)&Qp[g * 8 + 4];
        f32x4 q2 = *(const f32x4*)&Qp[32 + g * 8], q3 = *(const f32x4*)&Qp[32 + g * 8 + 4];
        f32x4 k0 = *(const f32x4*)&Kp[g * 8], k1 = *(const f32x4*)&Kp[g * 8 + 4];
        f32x4 k2 = *(const f32x4*)&Kp[32 + g * 8], k3 = *(const f32x4*)&Kp[32 + g * 8 + 4];

        float sx = xyz[(size_t)p * 3], sy = xyz[(size_t)p * 3 + 1], sz = xyz[(size_t)p * 3 + 2];
        float dx = sx - xyz[(size_t)nb * 3];
        float dy = sy - xyz[(size_t)nb * 3 + 1];
        float dz = sz - xyz[(size_t)nb * 3 + 2];

        short8 ha[2];
#pragma unroll
        for (int kt = 0; kt < 2; ++kt) {
            short8 hv;
#pragma unroll
            for (int hb = 0; hb < 2; ++hb) {
                int ch = kt * 32 + g * 8 + hb * 4;
                f32x4 w0 = *(const f32x4*)&d1s[0][ch];
                f32x4 w1 = *(const f32x4*)&d1s[1][ch];
                f32x4 w2 = *(const f32x4*)&d1s[2][ch];
                f32x4 bb_ = *(const f32x4*)&d1s[3][ch];
#pragma unroll
                for (int j = 0; j < 4; ++j) {
                    float h = bb_[j] + dx * w0[j] + dy * w1[j] + dz * w2[j];
                    hv[hb * 4 + j] = f2bf(fmaxf(h, 0.f));
                }
            }
            ha[kt] = hv;
        }

        f32x4 pe[4];
#pragma unroll
        for (int ct = 0; ct < 4; ++ct) {
            f32x4 acc = {0.f, 0.f, 0.f, 0.f};
            acc = __builtin_amdgcn_mfma_f32_16x16x32_bf16(ha[0], bd2[0][ct], acc, 0, 0, 0);
            acc = __builtin_amdgcn_mfma_f32_16x16x32_bf16(ha[1], bd2[1][ct], acc, 0, 0, 0);
#pragma unroll
            for (int r = 0; r < 4; ++r) pe[ct][r] = acc[r] + b2c[ct];
        }

#pragma unroll
        for (int ct = 0; ct < 4; ++ct)
#pragma unroll
            for (int r = 0; r < 4; ++r)
                tb[(4 * g + r) * TSTR + ct * 16 + cc] = pe[ct][r];
        short8 xa[2];
        {
            f32x4 p0 = *(const f32x4*)&tb[cc * TSTR + g * 8];
            f32x4 p1 = *(const f32x4*)&tb[cc * TSTR + g * 8 + 4];
            f32x4 p2 = *(const f32x4*)&tb[cc * TSTR + 32 + g * 8];
            f32x4 p3 = *(const f32x4*)&tb[cc * TSTR + 32 + g * 8 + 4];
            f32x4 x0 = q0 - k0 + p0, x1 = q1 - k1 + p1;
            f32x4 x2 = q2 - k2 + p2, x3 = q3 - k3 + p3;
            short8 v0, v1;
#pragma unroll
            for (int j = 0; j < 4; ++j) {
                v0[j] = f2bf(x0[j]); v0[4 + j] = f2bf(x1[j]);
                v1[j] = f2bf(x2[j]); v1[4 + j] = f2bf(x3[j]);
            }
            xa[0] = v0; xa[1] = v1;
        }

        f32x4 h2[4];
#pragma unroll
        for (int ct = 0; ct < 4; ++ct) {
            f32x4 acc = {0.f, 0.f, 0.f, 0.f};
            acc = __builtin_amdgcn_mfma_f32_16x16x32_bf16(xa[0], bg1[0][ct], acc, 0, 0, 0);
            acc = __builtin_amdgcn_mfma_f32_16x16x32_bf16(xa[1], bg1[1][ct], acc, 0, 0, 0);
#pragma unroll
            for (int r = 0; r < 4; ++r) h2[ct][r] = fmaxf(acc[r] + gb1c[ct], 0.f);
        }

#pragma unroll
        for (int ct = 0; ct < 4; ++ct)
#pragma unroll
            for (int r = 0; r < 4; ++r)
                tb[(4 * g + r) * TSTR + ct * 16 + cc] = h2[ct][r];
        short8 h2a[2];
        {
            f32x4 p0 = *(const f32x4*)&tb[cc * TSTR + g * 8];
            f32x4 p1 = *(const f32x4*)&tb[cc * TSTR + g * 8 + 4];
            f32x4 p2 = *(const f32x4*)&tb[cc * TSTR + 32 + g * 8];
            f32x4 p3 = *(const f32x4*)&tb[cc * TSTR + 32 + g * 8 + 4];
            short8 v0, v1;
#pragma unroll
            for (int j = 0; j < 4; ++j) {
                v0[j] = f2bf(p0[j]); v0[4 + j] = f2bf(p1[j]);
                v1[j] = f2bf(p2[j]); v1[4 + j] = f2bf(p3[j]);
            }
            h2a[0] = v0; h2a[1] = v1;
        }

        f32x4 lg[4];
#pragma unroll
        for (int ct = 0; ct < 4; ++ct) {
            f32x4 acc = {0.f, 0.f, 0.f, 0.f};
            acc = __builtin_amdgcn_mfma_f32_16x16x32_bf16(h2a[0], bg2[0][ct], acc, 0, 0, 0);
            acc = __builtin_amdgcn_mfma_f32_16x16x32_bf16(h2a[1], bg2[1][ct], acc, 0, 0, 0);
#pragma unroll
            for (int r = 0; r < 4; ++r) lg[ct][r] = acc[r] + gb2c[ct];
        }

        const float* Vp = Vf + (size_t)nb * 64;
        {
            f32x4 v0 = *(const f32x4*)&Vp[g * 8], v1 = *(const f32x4*)&Vp[g * 8 + 4];
            f32x4 v2 = *(const f32x4*)&Vp[32 + g * 8], v3 = *(const f32x4*)&Vp[32 + g * 8 + 4];
            *(f32x4*)&tb[cc * TSTR + g * 8] = v0;
            *(f32x4*)&tb[cc * TSTR + g * 8 + 4] = v1;
            *(f32x4*)&tb[cc * TSTR + 32 + g * 8] = v2;
            *(f32x4*)&tb[cc * TSTR + 32 + g * 8 + 4] = v3;
        }
        f32x4 vc[4];
#pragma unroll
        for (int ct = 0; ct < 4; ++ct)
#pragma unroll
            for (int r = 0; r < 4; ++r)
                vc[ct][r] = tb[(4 * g + r) * TSTR + ct * 16 + cc];

        float part[4];
#pragma unroll
        for (int ct = 0; ct < 4; ++ct) {
            float m = fmaxf(fmaxf(lg[ct][0], lg[ct][1]), fmaxf(lg[ct][2], lg[ct][3]));
            m = fmaxf(m, __shfl_xor(m, 16));
            m = fmaxf(m, __shfl_xor(m, 32));
            float e0 = __expf(lg[ct][0] - m), e1 = __expf(lg[ct][1] - m);
            float e2 = __expf(lg[ct][2] - m), e3 = __expf(lg[ct][3] - m);
            float s = e0 + e1 + e2 + e3;
            s += __shfl_xor(s, 16);
            s += __shfl_xor(s, 32);
            float inv = 1.0f / s;
            float pt = 0.f;
            pt = fmaf(e0 * inv, vc[ct][0] + pe[ct][0], pt);
            pt = fmaf(e1 * inv, vc[ct][1] + pe[ct][1], pt);
            pt = fmaf(e2 * inv, vc[ct][2] + pe[ct][2], pt);
            pt = fmaf(e3 * inv, vc[ct][3] + pe[ct][3], pt);
            pt += __shfl_xor(pt, 16);
            pt += __shfl_xor(pt, 32);
            part[ct] = pt;
        }
        float resv = part[0];
        resv = is1 ? part[1] : resv;
        resv = is2 ? part[2] : resv;
        resv = is3 ? part[3] : resv;
        resv += feats[(size_t)p * 64 + lane];
        out[(size_t)p * 64 + lane] = resv;
        lsum += resv;
        lsq = fmaf(resv, resv, lsq);
    }
    atomicAdd(&bns[lane], lsum);
    atomicAdd(&bnq[lane], lsq);
    __syncthreads();
    if (tid < 64) {
        atomicAdd(&gsum[tid], bns[tid]);
        atomicAdd(&gsq[tid], bnq[tid]);
    }
}

// ---------------- BatchNorm finalize (in place on d_out) ----------------
__global__ __launch_bounds__(256) void bn_final_kernel(float* __restrict__ out,
                                                       const float* __restrict__ gsum,
                                                       const float* __restrict__ gsq,
                                                       const float* __restrict__ bnw,
                                                       const float* __restrict__ bnb) {
    __shared__ float sc[64], sh[64];
    int tid = threadIdx.x;
    if (tid < 64) {
        const float invN = 1.0f / (float)(BB * NN);
        float mean = gsum[tid] * invN;
        float var = gsq[tid] * invN - mean * mean;
        float inv = rsqrtf(var + 1e-5f);
        float scale = inv * bnw[tid];
        sc[tid] = scale;
        sh[tid] = bnb[tid] - mean * scale;
    }
    __syncthreads();
    size_t total = (size_t)BB * NN * 64;
    for (size_t i = (size_t)blockIdx.x * 256 + tid; i < total; i += (size_t)gridDim.x * 256) {
        int c = (int)(i & 63);
        out[i] = fmaf(out[i], sc[c], sh[c]);
    }
}

extern "C" void kernel_launch(void* const* d_in, const int* in_sizes, int n_in,
                              void* d_out, int out_size, void* d_ws, size_t ws_size,
                              hipStream_t stream) {
    const float* xyz = (const float*)d_in[0];
    const float* feats = (const float*)d_in[1];
    const float* Wq = (const float*)d_in[2];
    const float* Wk = (const float*)d_in[3];
    const float* Wv = (const float*)d_in[4];
    const float* d1w = (const float*)d_in[5];
    const float* d1b = (const float*)d_in[6];
    const float* d2w = (const float*)d_in[7];
    const float* d2b = (const float*)d_in[8];
    const float* g1w = (const float*)d_in[9];
    const float* g1b = (const float*)d_in[10];
    const float* g2w = (const float*)d_in[11];
    const float* g2b = (const float*)d_in[12];
    const float* bnw = (const float*)d_in[13];
    const float* bnb = (const float*)d_in[14];
    float* out = (float*)d_out;

    char* ws = (char*)d_ws;
    size_t off = 0;
    int* knnIdx = (int*)(ws + off); off += (size_t)BB * NN * 16 * 4;
    float* Q = (float*)(ws + off); off += (size_t)BB * NN * 64 * 4;
    float* Kf = (float*)(ws + off); off += (size_t)BB * NN * 64 * 4;
    float* Vf = (float*)(ws + off); off += (size_t)BB * NN * 64 * 4;
    float* stats = (float*)(ws + off);  // 128 floats

    hipLaunchKernelGGL(qkv_kernel, dim3(512), dim3(256), 0, stream,
                       feats, Wq, Wk, Wv, Q, Kf, Vf, stats);
    hipLaunchKernelGGL(knn_kernel, dim3(BB * 64), dim3(1024), 0, stream, xyz, knnIdx);
    hipLaunchKernelGGL(attn_kernel, dim3(1024), dim3(256), 0, stream,
                       xyz, feats, Q, Kf, Vf, knnIdx,
                       d1w, d1b, d2w, d2b, g1w, g1b, g2w, g2b,
                       out, stats, stats + 64);
    hipLaunchKernelGGL(bn_final_kernel, dim3(512), dim3(256), 0, stream,
                       out, stats, stats + 64, bnw, bnb);
}

// Round 15
// 236.490 us; speedup vs baseline: 1.0720x; 1.0399x over previous
//
#include <hip/hip_runtime.h>
#include <hip/hip_bf16.h>

#define BB 8
#define NN 4096
#define DD 64

typedef __attribute__((ext_vector_type(8))) short short8;
typedef __attribute__((ext_vector_type(4))) float f32x4;

__device__ __forceinline__ short f2bf(float f) {
    __hip_bfloat16 h = __float2bfloat16(f);
    return __builtin_bit_cast(short, h);
}

__device__ __forceinline__ float bcastf(float x, int l) {
    return __int_as_float(__builtin_amdgcn_readlane(__float_as_int(x), l));
}

// count of set bits in mask strictly below this lane (64-lane mbcnt idiom)
__device__ __forceinline__ int mbcnt64(unsigned long long mask) {
    return __builtin_amdgcn_mbcnt_hi((unsigned)(mask >> 32),
           __builtin_amdgcn_mbcnt_lo((unsigned)mask, 0));
}

// ---------------- exact kNN: wave = 1 query (round-10 proven kernel, verbatim) ----------------
__device__ __forceinline__ void bsort64(float& d, int& i, int lane) {
#pragma unroll
    for (int s = 2; s <= 64; s <<= 1) {
#pragma unroll
        for (int m = s >> 1; m >= 1; m >>= 1) {
            float dp = __shfl_xor(d, m);
            int ip = __shfl_xor(i, m);
            bool up = ((lane & s) == 0);
            bool lower = ((lane & m) == 0);
            bool less = (d < dp) || (d == dp && i < ip);
            bool takeMine = (less == (up == lower));
            d = takeMine ? d : dp;
            i = takeMine ? i : ip;
        }
    }
}

__device__ __forceinline__ float sq3(float x, float y, float z) {
    return __fadd_rn(__fadd_rn(__fmul_rn(x, x), __fmul_rn(y, y)), __fmul_rn(z, z));
}

// dist from precomputed-sq float4 entry; rounding chain identical to prior pdist
__device__ __forceinline__ float pdistv(float qx, float qy, float qz, float sqq, float4 c4) {
    float dot = __fadd_rn(__fadd_rn(__fmul_rn(qx, c4.x), __fmul_rn(qy, c4.y)),
                          __fmul_rn(qz, c4.z));
    return __fadd_rn(__fadd_rn(sqq, c4.w), -__fmul_rn(2.0f, dot));
}

// block = 1024 threads = 16 waves sharing one X4 stage; 64 queries per block (4 per wave)
// grid = BB * 64 = 512 blocks; LDS 72KB -> 2 blocks/CU -> 8 waves/SIMD.
__global__ __launch_bounds__(1024) void knn_kernel(const float* __restrict__ xyz,
                                                   int* __restrict__ knnIdx) {
    __shared__ __align__(16) float4 X4[NN];     // (x,y,z,|c|^2), 64KB
    __shared__ float bufD[16][64];
    __shared__ int bufI[16][64];
    int tid = threadIdx.x;
    int b = blockIdx.x >> 6;        // 64 blocks per batch
    int qgroup = blockIdx.x & 63;   // 64 queries per block
    const float* xb = xyz + (size_t)b * NN * 3;
    for (int i = tid; i < NN; i += 1024) {
        float x = xb[i * 3], y = xb[i * 3 + 1], z = xb[i * 3 + 2];
        X4[i] = make_float4(x, y, z, sq3(x, y, z));
    }
    __syncthreads();

    int wid = tid >> 6, lane = tid & 63;
    float* bD = bufD[wid];
    int* bI = bufI[wid];

    for (int qi = 0; qi < 4; ++qi) {
        int qq = qgroup * 64 + wid * 4 + qi;
        float4 qv = X4[qq];
        float qx = qv.x, qy = qv.y, qz = qv.z, sqq = qv.w;
        // round 0: candidates 0..63
        float d0 = pdistv(qx, qy, qz, sqq, X4[lane]);
        int i0 = lane;
        bsort64(d0, i0, lane);
        if (lane < 16) { bD[lane] = d0; bI[lane] = i0; }
        int count = 16;
        float t = __shfl(d0, 15);

        for (int r = 1; r < 64; ++r) {
            int cidx = r * 64 + lane;
            float dc = pdistv(qx, qy, qz, sqq, X4[cidx]);
            bool live = dc < t;
            unsigned long long mask = __ballot(live);
            while (mask) {
                int avail = 64 - count;
                int pos = mbcnt64(mask);
                if (live && pos < avail) {
                    bD[count + pos] = dc;
                    bI[count + pos] = cidx;
                }
                int nq = __popcll(mask);
                if (nq <= avail) {
                    count += nq;
                    mask = 0;
                } else {
                    count = 64;
                    live = live && (pos >= avail);
                    // sort-cut to exact top-16 of all seen so far
                    float sd = bD[lane];
                    int si = bI[lane];
                    bsort64(sd, si, lane);
                    if (lane < 16) { bD[lane] = sd; bI[lane] = si; }
                    count = 16;
                    t = __shfl(sd, 15);
                    live = live && (dc < t);
                    mask = __ballot(live);
                }
            }
        }
        float fd = (lane < count) ? bD[lane] : 3.0e38f;
        int fi = (lane < count) ? bI[lane] : 0x7fffffff;
        bsort64(fd, fi, lane);
        if (lane < 16) knnIdx[((size_t)b * NN + qq) * 16 + lane] = fi;
    }
}

// ---------------- q/k/v projections (f32, readlane broadcast) + stats zeroing ----------------
__global__ __launch_bounds__(256) void qkv_kernel(const float* __restrict__ feats,
                                                  const float* __restrict__ Wq,
                                                  const float* __restrict__ Wk,
                                                  const float* __restrict__ Wv,
                                                  float* __restrict__ Q,
                                                  float* __restrict__ Kf,
                                                  float* __restrict__ Vf,
                                                  float* __restrict__ stats) {
    __shared__ float Aq[4096], Ak[4096], Av[4096];
    int tid = threadIdx.x;
    if (blockIdx.x == 0 && tid < 128) stats[tid] = 0.f;
    for (int i = tid; i < 4096; i += 256) { Aq[i] = Wq[i]; Ak[i] = Wk[i]; Av[i] = Wv[i]; }
    __syncthreads();
    int lane = tid & 63, wid = tid >> 6;
    int gw = blockIdx.x * 4 + wid, nw = gridDim.x * 4;
    for (int r = gw; r < BB * NN; r += nw) {
        float f = feats[(size_t)r * 64 + lane];
        float aq = 0.f, ak = 0.f, av = 0.f;
#pragma unroll 8
        for (int h = 0; h < 64; ++h) {
            float s = bcastf(f, h);
            aq = fmaf(s, Aq[h * 64 + lane], aq);
            ak = fmaf(s, Ak[h * 64 + lane], ak);
            av = fmaf(s, Av[h * 64 + lane], av);
        }
        Q[(size_t)r * 64 + lane] = aq;
        Kf[(size_t)r * 64 + lane] = ak;
        Vf[(size_t)r * 64 + lane] = av;
    }
}

// ---------------- fused MFMA attention: wave = 1 point ----------------
#define TSTR 68

__global__ __launch_bounds__(256, 2) void attn_kernel(
    const float* __restrict__ xyz, const float* __restrict__ feats,
    const float* __restrict__ Q, const float* __restrict__ Kf, const float* __restrict__ Vf,
    const int* __restrict__ knnIdx,
    const float* __restrict__ d1w, const float* __restrict__ d1b,
    const float* __restrict__ d2w, const float* __restrict__ d2b,
    const float* __restrict__ g1w, const float* __restrict__ g1b,
    const float* __restrict__ g2w, const float* __restrict__ g2b,
    float* __restrict__ out, float* __restrict__ gsum, float* __restrict__ gsq) {
    __shared__ float d1s[4][64];
    __shared__ __align__(16) float tbuf[4][16 * TSTR];
    __shared__ float bns[64], bnq[64];
    int tid = threadIdx.x;
    if (tid < 256) {
        int a = tid >> 6, ch = tid & 63;
        d1s[a][ch] = (a < 3) ? d1w[a * 64 + ch] : d1b[ch];
    }
    if (tid < 64) { bns[tid] = 0.f; bnq[tid] = 0.f; }
    __syncthreads();

    int lane = tid & 63, wid = tid >> 6;
    int cc = lane & 15, g = lane >> 4;
    float* tb = tbuf[wid];

    short8 bd2[2][4], bg1[2][4], bg2[2][4];
#pragma unroll
    for (int kt = 0; kt < 2; ++kt)
#pragma unroll
        for (int ct = 0; ct < 4; ++ct) {
            short8 f2, fg1, fg2;
#pragma unroll
            for (int j = 0; j < 8; ++j) {
                int kk = kt * 32 + g * 8 + j, col = ct * 16 + cc;
                f2[j] = f2bf(d2w[kk * 64 + col]);
                fg1[j] = f2bf(g1w[kk * 64 + col]);
                fg2[j] = f2bf(g2w[kk * 64 + col]);
            }
            bd2[kt][ct] = f2; bg1[kt][ct] = fg1; bg2[kt][ct] = fg2;
        }
    float b2c[4], gb1c[4], gb2c[4];
#pragma unroll
    for (int ct = 0; ct < 4; ++ct) {
        b2c[ct] = d2b[ct * 16 + cc];
        gb1c[ct] = g1b[ct * 16 + cc];
        gb2c[ct] = g2b[ct * 16 + cc];
    }
    bool is1 = (g == 1), is2 = (g == 2), is3 = (g == 3);

    int gw = blockIdx.x * 4 + wid, nw = gridDim.x * 4;
    float lsum = 0.f, lsq = 0.f;

    for (int p = gw; p < BB * NN; p += nw) {
        int b = p >> 12;
        int idxA = knnIdx[(size_t)p * 16 + cc];
        int nb = (b << 12) + idxA;

        const float* Qp = Q + (size_t)p * 64;
        const float* Kp = Kf + (size_t)nb * 64;
        f32x4 q0 = *(const f32x4*)&Qp[g * 8], q1 = *(const f32x4*)&Qp[g * 8 + 4];
        f32x4 q2 = *(const f32x4*)&Qp[32 + g * 8], q3 = *(const f32x4*)&Qp[32 + g * 8 + 4];
        f32x4 k0 = *(const f32x4*)&Kp[g * 8], k1 = *(const f32x4*)&Kp[g * 8 + 4];
        f32x4 k2 = *(const f32x4*)&Kp[32 + g * 8], k3 = *(const f32x4*)&Kp[32 + g * 8 + 4];

        float sx = xyz[(size_t)p * 3], sy = xyz[(size_t)p * 3 + 1], sz = xyz[(size_t)p * 3 + 2];
        float dx = sx - xyz[(size_t)nb * 3];
        float dy = sy - xyz[(size_t)nb * 3 + 1];
        float dz = sz - xyz[(size_t)nb * 3 + 2];

        short8 ha[2];
#pragma unroll
        for (int kt = 0; kt < 2; ++kt) {
            short8 hv;
#pragma unroll
            for (int hb = 0; hb < 2; ++hb) {
                int ch = kt * 32 + g * 8 + hb * 4;
                f32x4 w0 = *(const f32x4*)&d1s[0][ch];
                f32x4 w1 = *(const f32x4*)&d1s[1][ch];
                f32x4 w2 = *(const f32x4*)&d1s[2][ch];
                f32x4 bb_ = *(const f32x4*)&d1s[3][ch];
#pragma unroll
                for (int j = 0; j < 4; ++j) {
                    float h = bb_[j] + dx * w0[j] + dy * w1[j] + dz * w2[j];
                    hv[hb * 4 + j] = f2bf(fmaxf(h, 0.f));
                }
            }
            ha[kt] = hv;
        }

        f32x4 pe[4];
#pragma unroll
        for (int ct = 0; ct < 4; ++ct) {
            f32x4 acc = {0.f, 0.f, 0.f, 0.f};
            acc = __builtin_amdgcn_mfma_f32_16x16x32_bf16(ha[0], bd2[0][ct], acc, 0, 0, 0);
            acc = __builtin_amdgcn_mfma_f32_16x16x32_bf16(ha[1], bd2[1][ct], acc, 0, 0, 0);
#pragma unroll
            for (int r = 0; r < 4; ++r) pe[ct][r] = acc[r] + b2c[ct];
        }

#pragma unroll
        for (int ct = 0; ct < 4; ++ct)
#pragma unroll
            for (int r = 0; r < 4; ++r)
                tb[(4 * g + r) * TSTR + ct * 16 + cc] = pe[ct][r];
        short8 xa[2];
        {
            f32x4 p0 = *(const f32x4*)&tb[cc * TSTR + g * 8];
            f32x4 p1 = *(const f32x4*)&tb[cc * TSTR + g * 8 + 4];
            f32x4 p2 = *(const f32x4*)&tb[cc * TSTR + 32 + g * 8];
            f32x4 p3 = *(const f32x4*)&tb[cc * TSTR + 32 + g * 8 + 4];
            f32x4 x0 = q0 - k0 + p0, x1 = q1 - k1 + p1;
            f32x4 x2 = q2 - k2 + p2, x3 = q3 - k3 + p3;
            short8 v0, v1;
#pragma unroll
            for (int j = 0; j < 4; ++j) {
                v0[j] = f2bf(x0[j]); v0[4 + j] = f2bf(x1[j]);
                v1[j] = f2bf(x2[j]); v1[4 + j] = f2bf(x3[j]);
            }
            xa[0] = v0; xa[1] = v1;
        }

        f32x4 h2[4];
#pragma unroll
        for (int ct = 0; ct < 4; ++ct) {
            f32x4 acc = {0.f, 0.f, 0.f, 0.f};
            acc = __builtin_amdgcn_mfma_f32_16x16x32_bf16(xa[0], bg1[0][ct], acc, 0, 0, 0);
            acc = __builtin_amdgcn_mfma_f32_16x16x32_bf16(xa[1], bg1[1][ct], acc, 0, 0, 0);
#pragma unroll
            for (int r = 0; r < 4; ++r) h2[ct][r] = fmaxf(acc[r] + gb1c[ct], 0.f);
        }

#pragma unroll
        for (int ct = 0; ct < 4; ++ct)
#pragma unroll
            for (int r = 0; r < 4; ++r)
                tb[(4 * g + r) * TSTR + ct * 16 + cc] = h2[ct][r];
        short8 h2a[2];
        {
            f32x4 p0 = *(const f32x4*)&tb[cc * TSTR + g * 8];
            f32x4 p1 = *(const f32x4*)&tb[cc * TSTR + g * 8 + 4];
            f32x4 p2 = *(const f32x4*)&tb[cc * TSTR + 32 + g * 8];
            f32x4 p3 = *(const f32x4*)&tb[cc * TSTR + 32 + g * 8 + 4];
            short8 v0, v1;
#pragma unroll
            for (int j = 0; j < 4; ++j) {
                v0[j] = f2bf(p0[j]); v0[4 + j] = f2bf(p1[j]);
                v1[j] = f2bf(p2[j]); v1[4 + j] = f2bf(p3[j]);
            }
            h2a[0] = v0; h2a[1] = v1;
        }

        f32x4 lg[4];
#pragma unroll
        for (int ct = 0; ct < 4; ++ct) {
            f32x4 acc = {0.f, 0.f, 0.f, 0.f};
            acc = __builtin_amdgcn_mfma_f32_16x16x32_bf16(h2a[0], bg2[0][ct], acc, 0, 0, 0);
            acc = __builtin_amdgcn_mfma_f32_16x16x32_bf16(h2a[1], bg2[1][ct], acc, 0, 0, 0);
#pragma unroll
            for (int r = 0; r < 4; ++r) lg[ct][r] = acc[r] + gb2c[ct];
        }

        const float* Vp = Vf + (size_t)nb * 64;
        {
            f32x4 v0 = *(const f32x4*)&Vp[g * 8], v1 = *(const f32x4*)&Vp[g * 8 + 4];
            f32x4 v2 = *(const f32x4*)&Vp[32 + g * 8], v3 = *(const f32x4*)&Vp[32 + g * 8 + 4];
            *(f32x4*)&tb[cc * TSTR + g * 8] = v0;
            *(f32x4*)&tb[cc * TSTR + g * 8 + 4] = v1;
            *(f32x4*)&tb[cc * TSTR + 32 + g * 8] = v2;
            *(f32x4*)&tb[cc * TSTR + 32 + g * 8 + 4] = v3;
        }
        f32x4 vc[4];
#pragma unroll
        for (int ct = 0; ct < 4; ++ct)
#pragma unroll
            for (int r = 0; r < 4; ++r)
                vc[ct][r] = tb[(4 * g + r) * TSTR + ct * 16 + cc];

        float part[4];
#pragma unroll
        for (int ct = 0; ct < 4; ++ct) {
            float m = fmaxf(fmaxf(lg[ct][0], lg[ct][1]), fmaxf(lg[ct][2], lg[ct][3]));
            m = fmaxf(m, __shfl_xor(m, 16));
            m = fmaxf(m, __shfl_xor(m, 32));
            float e0 = __expf(lg[ct][0] - m), e1 = __expf(lg[ct][1] - m);
            float e2 = __expf(lg[ct][2] - m), e3 = __expf(lg[ct][3] - m);
            float s = e0 + e1 + e2 + e3;
            s += __shfl_xor(s, 16);
            s += __shfl_xor(s, 32);
            float inv = 1.0f / s;
            float pt = 0.f;
            pt = fmaf(e0 * inv, vc[ct][0] + pe[ct][0], pt);
            pt = fmaf(e1 * inv, vc[ct][1] + pe[ct][1], pt);
            pt = fmaf(e2 * inv, vc[ct][2] + pe[ct][2], pt);
            pt = fmaf(e3 * inv, vc[ct][3] + pe[ct][3], pt);
            pt += __shfl_xor(pt, 16);
            pt += __shfl_xor(pt, 32);
            part[ct] = pt;
        }
        float resv = part[0];
        resv = is1 ? part[1] : resv;
        resv = is2 ? part[2] : resv;
        resv = is3 ? part[3] : resv;
        resv += feats[(size_t)p * 64 + lane];
        out[(size_t)p * 64 + lane] = resv;
        lsum += resv;
        lsq = fmaf(resv, resv, lsq);
    }
    atomicAdd(&bns[lane], lsum);
    atomicAdd(&bnq[lane], lsq);
    __syncthreads();
    if (tid < 64) {
        atomicAdd(&gsum[tid], bns[tid]);
        atomicAdd(&gsq[tid], bnq[tid]);
    }
}

// ---------------- BatchNorm finalize (in place on d_out) ----------------
__global__ __launch_bounds__(256) void bn_final_kernel(float* __restrict__ out,
                                                       const float* __restrict__ gsum,
                                                       const float* __restrict__ gsq,
                                                       const float* __restrict__ bnw,
                                                       const float* __restrict__ bnb) {
    __shared__ float sc[64], sh[64];
    int tid = threadIdx.x;
    if (tid < 64) {
        const float invN = 1.0f / (float)(BB * NN);
        float mean = gsum[tid] * invN;
        float var = gsq[tid] * invN - mean * mean;
        float inv = rsqrtf(var + 1e-5f);
        float scale = inv * bnw[tid];
        sc[tid] = scale;
        sh[tid] = bnb[tid] - mean * scale;
    }
    __syncthreads();
    size_t total = (size_t)BB * NN * 64;
    for (size_t i = (size_t)blockIdx.x * 256 + tid; i < total; i += (size_t)gridDim.x * 256) {
        int c = (int)(i & 63);
        out[i] = fmaf(out[i], sc[c], sh[c]);
    }
}

extern "C" void kernel_launch(void* const* d_in, const int* in_sizes, int n_in,
                              void* d_out, int out_size, void* d_ws, size_t ws_size,
                              hipStream_t stream) {
    const float* xyz = (const float*)d_in[0];
    const float* feats = (const float*)d_in[1];
    const float* Wq = (const float*)d_in[2];
    const float* Wk = (const float*)d_in[3];
    const float* Wv = (const float*)d_in[4];
    const float* d1w = (const float*)d_in[5];
    const float* d1b = (const float*)d_in[6];
    const float* d2w = (const float*)d_in[7];
    const float* d2b = (const float*)d_in[8];
    const float* g1w = (const float*)d_in[9];
    const float* g1b = (const float*)d_in[10];
    const float* g2w = (const float*)d_in[11];
    const float* g2b = (const float*)d_in[12];
    const float* bnw = (const float*)d_in[13];
    const float* bnb = (const float*)d_in[14];
    float* out = (float*)d_out;

    char* ws = (char*)d_ws;
    size_t off = 0;
    int* knnIdx = (int*)(ws + off); off += (size_t)BB * NN * 16 * 4;
    float* Q = (float*)(ws + off); off += (size_t)BB * NN * 64 * 4;
    float* Kf = (float*)(ws + off); off += (size_t)BB * NN * 64 * 4;
    float* Vf = (float*)(ws + off); off += (size_t)BB * NN * 64 * 4;
    float* stats = (float*)(ws + off);  // 128 floats

    hipLaunchKernelGGL(qkv_kernel, dim3(512), dim3(256), 0, stream,
                       feats, Wq, Wk, Wv, Q, Kf, Vf, stats);
    hipLaunchKernelGGL(knn_kernel, dim3(BB * 64), dim3(1024), 0, stream, xyz, knnIdx);
    hipLaunchKernelGGL(attn_kernel, dim3(512), dim3(256), 0, stream,
                       xyz, feats, Q, Kf, Vf, knnIdx,
                       d1w, d1b, d2w, d2b, g1w, g1b, g2w, g2b,
                       out, stats, stats + 64);
    hipLaunchKernelGGL(bn_final_kernel, dim3(512), dim3(256), 0, stream,
                       out, stats, stats + 64, bnw, bnb);
}